// Round 2
// 83.952 us; speedup vs baseline: 1.0650x; 1.0650x over previous
//
#include <hip/hip_runtime.h>

typedef unsigned short u16;
typedef __attribute__((ext_vector_type(8))) short short8;
typedef __attribute__((ext_vector_type(4))) float f32x4;

#define INVT 14.285714285714286f
#define EXP2C 20.609640474436812f  // (1/0.07) * log2(e)

__device__ __forceinline__ u16 f2bf(float f) {
  union { float f; unsigned u; } v; v.f = f;
  unsigned u = v.u;
  u += 0x7fffu + ((u >> 16) & 1u);  // round-to-nearest-even
  return (u16)(u >> 16);
}
__device__ __forceinline__ float bf2f(u16 h) {
  union { unsigned u; float f; } v; v.u = ((unsigned)h) << 16;
  return v.f;
}

__device__ __forceinline__ float fast_exp2(float x) {
#if __has_builtin(__builtin_amdgcn_exp2f)
  return __builtin_amdgcn_exp2f(x);
#else
  return exp2f(x);
#endif
}

// Kernel 1: normalize rows (fp32), cast to bf16; per-row diag term
// d_i = exp((||f_i||^2 - 1)/T) and positive-pair dot pos_i.
// Also zeroes E[8192] (2 floats per block) so the gemm atomics start clean.
__global__ void norm_kernel(const float* __restrict__ f1, const float* __restrict__ f2,
                            u16* __restrict__ F, float* __restrict__ dvec,
                            float* __restrict__ pos, float* __restrict__ E, int N) {
  int i = blockIdx.x;
  int l = threadIdx.x;  // 64 threads = 1 wave; 2 elements/thread
  if (l < 2) E[2 * i + l] = 0.0f;  // 4096 blocks x 2 = 8192
  const float* a = f1 + (size_t)i * 128;
  const float* b = f2 + (size_t)i * 128;
  float a0 = a[l], a1 = a[l + 64];
  float b0 = b[l], b1 = b[l + 64];
  float sa = a0 * a0 + a1 * a1;
  float sb = b0 * b0 + b1 * b1;
#pragma unroll
  for (int o = 32; o; o >>= 1) { sa += __shfl_xor(sa, o); sb += __shfl_xor(sb, o); }
  float ia = 1.0f / fmaxf(sqrtf(sa), 1e-12f);
  float ib = 1.0f / fmaxf(sqrtf(sb), 1e-12f);
  u16 ba0 = f2bf(a0 * ia), ba1 = f2bf(a1 * ia);
  u16 bb0 = f2bf(b0 * ib), bb1 = f2bf(b1 * ib);
  u16* Fa = F + (size_t)i * 128;
  u16* Fb = F + (size_t)(i + N) * 128;
  Fa[l] = ba0; Fa[l + 64] = ba1;
  Fb[l] = bb0; Fb[l + 64] = bb1;
  // self/cross dots of the bf16-rounded values (what the MFMA will see)
  float fa0 = bf2f(ba0), fa1 = bf2f(ba1);
  float fb0 = bf2f(bb0), fb1 = bf2f(bb1);
  float s1 = fa0 * fa0 + fa1 * fa1;
  float s2 = fb0 * fb0 + fb1 * fb1;
  float cr = fa0 * fb0 + fa1 * fb1;
#pragma unroll
  for (int o = 32; o; o >>= 1) {
    s1 += __shfl_xor(s1, o); s2 += __shfl_xor(s2, o); cr += __shfl_xor(cr, o);
  }
  if (l == 0) {
    // same formula as the gemm epilogue so the diagonal cancellation is consistent
    dvec[i]     = fast_exp2(fmaf(s1, EXP2C, -EXP2C));
    dvec[i + N] = fast_exp2(fmaf(s2, EXP2C, -EXP2C));
    pos[i] = cr;
    pos[i + N] = cr;
  }
}

__device__ __forceinline__ void glds16(const u16* g, u16* l) {
  __builtin_amdgcn_global_load_lds((const __attribute__((address_space(1))) void*)g,
                                   (__attribute__((address_space(3))) void*)l,
                                   16, 0, 0);
}

// rotate-add within 16-lane DPP rows; 4 steps (1,2,4,8) -> all 16 lanes hold the sum
template <int CTRL>
__device__ __forceinline__ float ror_add(float x) {
  int r = __builtin_amdgcn_update_dpp(0, __float_as_int(x), CTRL, 0xF, 0xF, false);
  return x + __int_as_float(r);
}

// Kernel 2 (symmetric): for tile pair (bi<=bj) of S = F F^T, compute
// exp((s-1)/T); accumulate tile column-sums into E[bj*128+*] and (off-diag)
// tile row-sums into E[bi*128+*]. S symmetric => this covers every (i,j) once.
// 512 threads = 8 waves (4x2 grid of 32x64 output subtiles); K split in two
// 64-wide halves so the second half's staging overlaps the first half's MFMAs.
__global__ __launch_bounds__(512, 4) void gemm_exp_kernel(const u16* __restrict__ F,
                                                          float* __restrict__ E) {
  // LDS layout: [half h][row][8 granules of 8 bf16], XOR-swizzled within a half:
  // slot (h,row,c') holds global k-granule h*8 + (c' ^ (row&7)) of that row.
  __shared__ __align__(16) u16 At[2][128][64];  // 32 KB
  __shared__ __align__(16) u16 Bt[2][128][64];  // 32 KB
  __shared__ float colsum[128];
  __shared__ float rowsum[128];
  const int tid = threadIdx.x;
  const int wave = tid >> 6, lane = tid & 63;
  // triangular decode: p -> (bj=r, bi=c<=r)
  int p = blockIdx.x;
  int r = (int)((sqrtf(8.0f * (float)p + 1.0f) - 1.0f) * 0.5f);
  while ((r + 1) * (r + 2) / 2 <= p) ++r;
  while (r * (r + 1) / 2 > p) --r;
  const int bj = r, bi = p - r * (r + 1) / 2;
  const u16* __restrict__ Ab = F + (size_t)bi * (128 * 128);
  const u16* __restrict__ Bb = F + (size_t)bj * (128 * 128);
  if (tid < 128) { colsum[tid] = 0.0f; rowsum[tid] = 0.0f; }

  // Stage. Per wave: 2 chunks/half/tile; chunk = 64 lanes x 16B = 8 rows of one half.
  // Issue order: all 4 half-0 loads first, then the 4 half-1 loads.
  const int lrow = lane >> 3, lcol = lane & 7;
#pragma unroll
  for (int h = 0; h < 2; ++h)
#pragma unroll
    for (int t = 0; t < 2; ++t) {
      const int row = wave * 16 + t * 8 + lrow;
      const size_t gsrc = (size_t)(row * 16 + h * 8 + (lcol ^ (row & 7))) * 8;
      u16* da = (u16*)At + h * 8192 + (wave * 2 + t) * 512;
      u16* db = (u16*)Bt + h * 8192 + (wave * 2 + t) * 512;
      glds16(Ab + gsrc, da);
      glds16(Bb + gsrc, db);
    }

  const int wr = wave >> 1, wc = wave & 1;  // 4x2 waves, each 32x64
  const int q = lane >> 4, m = lane & 15;
  f32x4 acc[2][4];
#pragma unroll
  for (int fr = 0; fr < 2; ++fr)
#pragma unroll
    for (int cf = 0; cf < 4; ++cf) acc[fr][cf] = (f32x4)(0.0f);

  auto kstep = [&](int ks) {
    const int h = ks >> 1;
    const int c = (ks & 1) * 4 + q;  // k-granule within half (8 bf16 per granule)
    const u16* Ah = (const u16*)At + h * 8192;
    const u16* Bh = (const u16*)Bt + h * 8192;
    short8 av[2], bv[4];
#pragma unroll
    for (int fr = 0; fr < 2; ++fr) {
      int rr = wr * 32 + fr * 16 + m;
      av[fr] = *(const short8*)&Ah[rr * 64 + ((c ^ (rr & 7)) * 8)];
    }
#pragma unroll
    for (int cf = 0; cf < 4; ++cf) {
      int rr = wc * 64 + cf * 16 + m;
      bv[cf] = *(const short8*)&Bh[rr * 64 + ((c ^ (rr & 7)) * 8)];
    }
#pragma unroll
    for (int fr = 0; fr < 2; ++fr)
#pragma unroll
      for (int cf = 0; cf < 4; ++cf)
        acc[fr][cf] = __builtin_amdgcn_mfma_f32_16x16x32_bf16(av[fr], bv[cf], acc[fr][cf], 0, 0, 0);
  };

  // half-0 ready (own oldest 4 loads done + everyone past barrier); half-1 in flight
  asm volatile("s_waitcnt vmcnt(4) lgkmcnt(0)\n\ts_barrier" ::: "memory");
  kstep(0);
  kstep(1);
  asm volatile("s_waitcnt vmcnt(0)\n\ts_barrier" ::: "memory");
  kstep(2);
  kstep(3);

  // Epilogue. C-layout: col = m, row = q*4 + reg.
  float cs[4] = {0.f, 0.f, 0.f, 0.f};
  float rs[8] = {0.f, 0.f, 0.f, 0.f, 0.f, 0.f, 0.f, 0.f};
#pragma unroll
  for (int cf = 0; cf < 4; ++cf)
#pragma unroll
    for (int fr = 0; fr < 2; ++fr)
#pragma unroll
      for (int rg = 0; rg < 4; ++rg) {
        float e = fast_exp2(fmaf(acc[fr][cf][rg], EXP2C, -EXP2C));
        cs[cf] += e;
        rs[fr * 4 + rg] += e;
      }
  // column sums: reduce across quads (rows) -> q==0 holds the wave's 32-row total
#pragma unroll
  for (int cf = 0; cf < 4; ++cf) {
    cs[cf] += __shfl_xor(cs[cf], 16);
    cs[cf] += __shfl_xor(cs[cf], 32);
    if (q == 0) atomicAdd(&colsum[wc * 64 + cf * 16 + m], cs[cf]);
  }
  // row sums (off-diagonal tiles only): DPP rotate-add across the 16 m-lanes
  if (bi != bj) {
#pragma unroll
    for (int i = 0; i < 8; ++i) {
      float v = rs[i];
      v = ror_add<0x121>(v);  // row_ror:1
      v = ror_add<0x122>(v);  // row_ror:2
      v = ror_add<0x124>(v);  // row_ror:4
      v = ror_add<0x128>(v);  // row_ror:8
      if (m == i) atomicAdd(&rowsum[wr * 32 + (i >> 2) * 16 + q * 4 + (i & 3)], v);
    }
  }
  __syncthreads();
  if (tid < 128) {
    atomicAdd(&E[bj * 128 + tid], colsum[tid]);
    if (bi != bj) atomicAdd(&E[bi * 128 + tid], rowsum[tid]);
  }
}

// Kernel 3: single block; term_i = (pos_i-1)/T - log(E_i - d_i); mean; write out.
__global__ void finish_kernel(const float* __restrict__ E, const float* __restrict__ dvec,
                              const float* __restrict__ pos, float* __restrict__ out,
                              int TWO_N, float scale) {
  float t = 0.0f;
  for (int i = threadIdx.x; i < TWO_N; i += 1024)
    t += (pos[i] - 1.0f) * INVT - logf(E[i] - dvec[i]);
#pragma unroll
  for (int o = 32; o; o >>= 1) t += __shfl_xor(t, o);
  __shared__ float wsum[16];
  int wave = threadIdx.x >> 6, lane = threadIdx.x & 63;
  if (lane == 0) wsum[wave] = t;
  __syncthreads();
  if (threadIdx.x == 0) {
    float s = 0.0f;
#pragma unroll
    for (int k = 0; k < 16; ++k) s += wsum[k];
    out[0] = s * scale;
  }
}

extern "C" void kernel_launch(void* const* d_in, const int* in_sizes, int n_in,
                              void* d_out, int out_size, void* d_ws, size_t ws_size,
                              hipStream_t stream) {
  const float* f1 = (const float*)d_in[0];
  const float* f2 = (const float*)d_in[1];
  const int N = in_sizes[0] / 128;  // 4096
  const int TWO_N = 2 * N;          // 8192
  const int NB = TWO_N / 128;       // 64
  const int NTILES = NB * (NB + 1) / 2;  // 2080

  char* ws = (char*)d_ws;
  u16*   F    = (u16*)ws;                                   // 2N*128 bf16 = 2 MB
  float* dvec = (float*)(ws + (size_t)TWO_N * 128 * 2);     // 2N f32
  float* pos  = dvec + TWO_N;                               // 2N f32
  float* E    = pos + TWO_N;                                // 2N f32

  norm_kernel<<<N, 64, 0, stream>>>(f1, f2, F, dvec, pos, E, N);
  gemm_exp_kernel<<<NTILES, 512, 0, stream>>>(F, E);
  finish_kernel<<<1, 1024, 0, stream>>>(E, dvec, pos, (float*)d_out, TWO_N,
                                        -1.0f / (float)TWO_N);
}